// Round 1
// baseline (231.862 us; speedup 1.0000x reference)
//
#include <hip/hip_runtime.h>
#include <math.h>

// Problem constants (depth collapses to d=0 because of x[:, :, 0:1] slicing:
// conv1d is causal -> w[3]*xi[0]+b; scan at d=0 -> hs[0]=BX[0]; A_log unused).
#define NB   2
#define CM   96      // D_MODEL
#define CI   192     // D_INNER
#define CO   384     // 2*D_INNER
#define HP   24
#define WP   24
#define PX   576     // 24*24
#define KTOT 864     // 96*9
#define DTR  6
#define NDBC 38      // DT_RANK + 2*D_STATE

__device__ __forceinline__ float siluf(float x){ return x / (1.f + expf(-x)); }
__device__ __forceinline__ float softplusf(float x){ return x > 20.f ? x : log1pf(expf(x)); }

// ---- K0: transpose in_proj_w (l,o,k) -> (l,k,o) so conv weight loads coalesce over o
__global__ void transpose_w(const float* __restrict__ w, float* __restrict__ wT){
    int idx = blockIdx.x*256 + threadIdx.x;
    if (idx >= 2*KTOT*CO) return;
    int l = idx / (KTOT*CO);
    int r = idx % (KTOT*CO);
    int k = r / CO;
    int o = r % CO;
    wT[idx] = w[l*KTOT*CO + o*KTOT + k];
}

// ---- K1: rmsnorm over the W axis (axis=-1 in the reference!)
__global__ void rmsnorm_k(const float* __restrict__ x, long nStride, long cStride,
                          const float* __restrict__ nw, float* __restrict__ h){
    int idx = blockIdx.x*256 + threadIdx.x;   // over NB*CM*HP = 4608
    if (idx >= NB*CM*HP) return;
    int n = idx/(CM*HP); int r = idx%(CM*HP); int c = r/HP; int hh = r%HP;
    const float* xp = x + (long)n*nStride + (long)c*cStride + hh*WP;
    float ss = 0.f;
    #pragma unroll
    for (int w = 0; w < WP; w++){ float v = xp[w]; ss += v*v; }
    float sc = rsqrtf(ss*(1.0f/WP) + 1e-5f) * nw[c];
    float* hp = h + ((n*CM + c)*PX + hh*WP);
    #pragma unroll
    for (int w = 0; w < WP; w++) hp[w] = xp[w]*sc;
}

// ---- K2: 3x3 conv 96->384 (pad 1) fused with causal conv1d tap (w[3]) + SiLU gates
__global__ __launch_bounds__(256) void conv_k(
    const float* __restrict__ h, const float* __restrict__ wT,
    const float* __restrict__ c1w, const float* __restrict__ c1b,
    float* __restrict__ xi, float* __restrict__ sz)
{
    __shared__ float hs[CM][3][26];       // 29.25 KiB, broadcast reads -> conflict-free
    int n  = blockIdx.x;
    int hh = blockIdx.y;
    int og = blockIdx.z;                  // 0..5, 64-channel groups
    int tid = threadIdx.x;

    for (int idx = tid; idx < CM*3*26; idx += 256){
        int c = idx/78; int rem = idx%78; int j = rem/26; int wc = rem%26;
        int row = hh + j - 1;
        float v = 0.f;
        if (row >= 0 && row < HP && wc >= 1 && wc <= WP)
            v = h[(n*CM + c)*PX + row*WP + (wc-1)];
        hs[c][j][wc] = v;
    }
    __syncthreads();

    int ol = tid & 63;
    int o  = og*64 + ol;
    int w0 = (tid >> 6) * 6;              // 4 waves x 6 pixels = 24
    float acc[6] = {0,0,0,0,0,0};
    const float* wTo = wT + o;

    for (int c = 0; c < CM; c++){
        float r0[8], r1[8], r2[8];
        #pragma unroll
        for (int i = 0; i < 8; i++){
            r0[i] = hs[c][0][w0+i]; r1[i] = hs[c][1][w0+i]; r2[i] = hs[c][2][w0+i];
        }
        const float* wk = wTo + (c*9)*CO;
        #pragma unroll
        for (int dx = 0; dx < 3; dx++){
            float w00 = wk[(0*3+dx)*CO];
            float w10 = wk[(1*3+dx)*CO];
            float w20 = wk[(2*3+dx)*CO];
            #pragma unroll
            for (int p = 0; p < 6; p++)
                acc[p] += w00*r0[p+dx] + w10*r1[p+dx] + w20*r2[p+dx];
        }
    }

    if (o < CI){
        float w3 = c1w[o*4 + 3];
        float b  = c1b[o];
        float* xp = xi + (n*CI + o)*PX + hh*WP + w0;
        #pragma unroll
        for (int p = 0; p < 6; p++) xp[p] = siluf(acc[p]*w3 + b);
    } else {
        int oz = o - CI;
        float* zp = sz + (n*CI + oz)*PX + hh*WP + w0;
        #pragma unroll
        for (int p = 0; p < 6; p++) zp[p] = siluf(acc[p]);
    }
}

// ---- K3a: per-pixel SSM math (one wave per pixel)
__global__ __launch_bounds__(256) void ssm_k(
    const float* __restrict__ xi, const float* __restrict__ sz,
    const float* __restrict__ xpw,   // 38*192
    const float* __restrict__ dtw,   // 192*6
    const float* __restrict__ dtb,   // 192
    const float* __restrict__ Dp,    // 192
    float* __restrict__ outb)
{
    int wave = threadIdx.x >> 6;
    int lane = threadIdx.x & 63;
    int p = blockIdx.x*4 + wave;          // 0..1151 exactly
    int n = p / PX;
    int px = p % PX;
    const float* xib = xi + n*CI*PX + px;
    const float* szb = sz + n*CI*PX + px;
    float xiv[3], szv[3];
    #pragma unroll
    for (int t = 0; t < 3; t++){ int c = lane + 64*t; xiv[t] = xib[c*PX]; szv[t] = szb[c*PX]; }

    float dbc[NDBC];
    #pragma unroll
    for (int j = 0; j < NDBC; j++){
        float s = 0.f;
        #pragma unroll
        for (int t = 0; t < 3; t++){ int c = lane + 64*t; s += xiv[t]*xpw[j*CI + c]; }
        dbc[j] = s;
    }
    #pragma unroll
    for (int step = 1; step < 64; step <<= 1){
        #pragma unroll
        for (int j = 0; j < NDBC; j++) dbc[j] += __shfl_xor(dbc[j], step, 64);
    }
    float BC = 0.f;
    #pragma unroll
    for (int s = 0; s < 16; s++) BC += dbc[6+s]*dbc[22+s];

    #pragma unroll
    for (int t = 0; t < 3; t++){
        int c = lane + 64*t;
        float dl = dtb[c];
        #pragma unroll
        for (int r = 0; r < DTR; r++) dl += dbc[r]*dtw[c*DTR + r];
        dl = softplusf(dl);
        float y = xiv[t]*(dl*BC + Dp[c]);
        outb[(n*CI + c)*PX + px] = y*szv[t];
    }
}

// ---- K3b: out_proj 192->96 + residual
__global__ __launch_bounds__(576) void proj_k(
    const float* __restrict__ outb, const float* __restrict__ opw,
    const float* __restrict__ xres, long nStride, long cStride,
    float* __restrict__ xnext)
{
    int n = blockIdx.x;
    int m = blockIdx.y;
    int px = threadIdx.x;                 // 0..575
    const float* ob = outb + n*CI*PX + px;
    const float* wr = opw + m*CI;
    float acc0 = 0.f, acc1 = 0.f, acc2 = 0.f, acc3 = 0.f;
    for (int k = 0; k < CI; k += 4){
        acc0 += ob[(k+0)*PX]*wr[k+0];
        acc1 += ob[(k+1)*PX]*wr[k+1];
        acc2 += ob[(k+2)*PX]*wr[k+2];
        acc3 += ob[(k+3)*PX]*wr[k+3];
    }
    float acc = (acc0+acc1) + (acc2+acc3);
    acc += xres[(long)n*nStride + (long)m*cStride + px];
    xnext[(n*CM + m)*PX + px] = acc;
}

extern "C" void kernel_launch(void* const* d_in, const int* in_sizes, int n_in,
                              void* d_out, int out_size, void* d_ws, size_t ws_size,
                              hipStream_t stream) {
    const float* x_in = (const float*)d_in[0];   // (2,96,8,24,24)
    const float* ipw  = (const float*)d_in[1];   // (2,384,96,1,3,3)
    const float* c1w  = (const float*)d_in[2];   // (2,192,1,4,1,1)
    const float* c1b  = (const float*)d_in[3];   // (2,192)
    const float* xpw  = (const float*)d_in[4];   // (2,38,192)
    const float* dtw  = (const float*)d_in[5];   // (2,192,6)
    const float* dtb  = (const float*)d_in[6];   // (2,192)
    // d_in[7] = A_log: provably unused at depth 0 (multiplies h[-1]=0)
    const float* Dp   = (const float*)d_in[8];   // (2,192)
    const float* opw  = (const float*)d_in[9];   // (2,96,192)
    const float* nw   = (const float*)d_in[10];  // (2,1,96,1,1,1)

    float* ws   = (float*)d_ws;
    float* wT   = ws;                    // 2*864*384 = 663552
    float* hbuf = wT   + 2*KTOT*CO;      // 110592
    float* xib  = hbuf + NB*CM*PX;       // 221184
    float* szb  = xib  + NB*CI*PX;       // 221184
    float* outb = szb  + NB*CI*PX;       // 221184
    float* x1   = outb + NB*CI*PX;       // 110592

    transpose_w<<<(2*KTOT*CO + 255)/256, 256, 0, stream>>>(ipw, wT);

    // ---- layer 0 (input: depth-0 slice of x, strides of the (2,96,8,24,24) tensor)
    rmsnorm_k<<<(NB*CM*HP + 255)/256, 256, 0, stream>>>(x_in, 96L*8*PX, 8L*PX, nw + 0, hbuf);
    conv_k<<<dim3(NB, HP, 6), 256, 0, stream>>>(hbuf, wT + 0, c1w + 0, c1b + 0, xib, szb);
    ssm_k<<<NB*PX/4, 256, 0, stream>>>(xib, szb, xpw + 0, dtw + 0, dtb + 0, Dp + 0, outb);
    proj_k<<<dim3(NB, CM), 576, 0, stream>>>(outb, opw + 0, x_in, 96L*8*PX, 8L*PX, x1);

    // ---- layer 1 (input x1 is packed (2,96,24,24); writes final output)
    rmsnorm_k<<<(NB*CM*HP + 255)/256, 256, 0, stream>>>(x1, 96L*PX, (long)PX, nw + CM, hbuf);
    conv_k<<<dim3(NB, HP, 6), 256, 0, stream>>>(hbuf, wT + KTOT*CO, c1w + CI*4, c1b + CI, xib, szb);
    ssm_k<<<NB*PX/4, 256, 0, stream>>>(xib, szb, xpw + NDBC*CI, dtw + CI*DTR, dtb + CI, Dp + CI, outb);
    proj_k<<<dim3(NB, CM), 576, 0, stream>>>(outb, opw + CM*CI, x1, 96L*PX, (long)PX, (float*)d_out);
}

// Round 2
// 166.251 us; speedup vs baseline: 1.3946x; 1.3946x over previous
//
#include <hip/hip_runtime.h>
#include <math.h>

// Depth collapses to d=0 (x[:, :, 0:1] slicing): conv1d -> w[3]*xi+b,
// scan at d=0 -> hs[0]=BX[0] (A_log unused), y = xi*(delta*sum(B*C)+D).
#define NB   2
#define CM   96      // D_MODEL
#define CI   192     // D_INNER
#define CO   384     // 2*D_INNER
#define HP   24
#define WP   24
#define PX   576
#define DTR  6
#define NDBC 38
#define CSPLIT 4
#define CCH  24      // input channels per conv chunk

__device__ __forceinline__ float siluf(float x){ return x / (1.f + expf(-x)); }
__device__ __forceinline__ float softplusf(float x){ return x > 20.f ? x : log1pf(expf(x)); }

// ---- prep: pack in_proj weights (l,o,c,k) -> wQ[l][c][g][o][4] (k=0..7) + wR[l][c][o] (k=8)
//            and transpose out_proj (l,m,c) -> wpT[l][c][m]
#define NW_IN (2*CO*CM*9)      // 663552
#define WQ_L  (CM*2*CO*4)      // 294912 per layer
#define WR_L  (CM*CO)          // 36864 per layer
#define WP_L  (CI*CM)          // 18432 per layer
__global__ void prep_k(const float* __restrict__ ipw, const float* __restrict__ opw,
                       float* __restrict__ wQ, float* __restrict__ wR, float* __restrict__ wpT){
    int idx = blockIdx.x*256 + threadIdx.x;
    if (idx < NW_IN){
        int l = idx / (CO*CM*9);
        int r = idx % (CO*CM*9);
        int o = r / (CM*9);
        int r2 = r % (CM*9);
        int c = r2 / 9;
        int k = r2 % 9;
        float v = ipw[idx];
        if (k < 8) wQ[l*WQ_L + ((c*2 + (k>>2))*CO + o)*4 + (k&3)] = v;
        else       wR[l*WR_L + c*CO + o] = v;
    } else {
        int j = idx - NW_IN;
        if (j < 2*CI*CM){
            int l = j / (CI*CM);
            int r = j % (CI*CM);
            int c = r / CM;
            int m = r % CM;
            wpT[l*WP_L + c*CM + m] = opw[(l*CM + m)*CI + c];
        }
    }
}

// ---- conv: fused rmsnorm + 3x3 conv (pad 1), c-chunked partial sums.
// grid (NB*HP, 6 o-groups, CSPLIT c-chunks), block 256.
// acc layout: [cs][n][px][o]  (both stores here and loads in ssmproj are coalesced)
__global__ __launch_bounds__(256) void conv_k(
    const float* __restrict__ x, long nStr, long cStr,
    const float* __restrict__ nw,
    const float* __restrict__ wQ, const float* __restrict__ wR,
    float* __restrict__ acc)
{
    __shared__ float hs[CCH][3][26];
    __shared__ float scl[CCH][3];
    int bx = blockIdx.x;
    int og = blockIdx.y;
    int cs = blockIdx.z;
    int n = bx / HP, hh = bx % HP;
    int tid = threadIdx.x;
    int c0 = cs*CCH;

    if (tid < CCH*3){
        int c = tid/3, j = tid%3;
        int row = hh + j - 1;
        float s = 0.f;
        if (row >= 0 && row < HP){
            const float* xp = x + (long)n*nStr + (long)(c0+c)*cStr + row*WP;
            #pragma unroll
            for (int w = 0; w < WP; w++){ float v = xp[w]; s += v*v; }
            s = rsqrtf(s*(1.0f/WP) + 1e-5f) * nw[c0+c];
        }
        scl[c][j] = s;
    }
    __syncthreads();

    for (int idx = tid; idx < CCH*3*26; idx += 256){
        int c = idx/78; int rem = idx%78; int j = rem/26; int wc = rem%26;
        int row = hh + j - 1;
        float v = 0.f;
        if (row >= 0 && row < HP && wc >= 1 && wc <= WP)
            v = x[(long)n*nStr + (long)(c0+c)*cStr + row*WP + (wc-1)] * scl[c][j];
        hs[c][j][wc] = v;
    }
    __syncthreads();

    int ol = tid & 63;
    int o  = og*64 + ol;
    int w0 = (tid >> 6) * 6;
    float acc6[6] = {0,0,0,0,0,0};
    const float4* wq4 = (const float4*)wQ;

    for (int c = 0; c < CCH; c++){
        int cg = c0 + c;
        float4 wa = wq4[(cg*2+0)*CO + o];   // k0..3: (0,0)(0,1)(0,2)(1,0)
        float4 wb = wq4[(cg*2+1)*CO + o];   // k4..7: (1,1)(1,2)(2,0)(2,1)
        float w8 = wR[cg*CO + o];           // k8:    (2,2)
        float r0[8], r1[8], r2[8];
        #pragma unroll
        for (int i = 0; i < 8; i++){
            r0[i] = hs[c][0][w0+i]; r1[i] = hs[c][1][w0+i]; r2[i] = hs[c][2][w0+i];
        }
        #pragma unroll
        for (int p = 0; p < 6; p++){
            acc6[p] += wa.x*r0[p]   + wa.y*r0[p+1] + wa.z*r0[p+2]
                     + wa.w*r1[p]   + wb.x*r1[p+1] + wb.y*r1[p+2]
                     + wb.z*r2[p]   + wb.w*r2[p+1] + w8  *r2[p+2];
        }
    }

    float* ap = acc + ((long)(cs*NB + n)*PX + hh*WP + w0)*CO + o;
    #pragma unroll
    for (int p = 0; p < 6; p++) ap[p*CO] = acc6[p];
}

// ---- ssmproj: sum partials -> conv1d tap + SiLU gates -> x_proj/dt/BC -> gate ->
//               out_proj + residual. block 256 = 4 waves = 4 pixels; grid NB*PX/4.
__global__ __launch_bounds__(256) void ssmproj_k(
    const float* __restrict__ acc,
    const float* __restrict__ c1w, const float* __restrict__ c1b,
    const float* __restrict__ xpw, const float* __restrict__ dtw,
    const float* __restrict__ dtb, const float* __restrict__ Dp,
    const float* __restrict__ wpT,
    const float* __restrict__ xres, long nStrR, long cStrR,
    float* __restrict__ dst)
{
    __shared__ float gl[4][CI];
    int wave = threadIdx.x >> 6, lane = threadIdx.x & 63;
    int p0 = blockIdx.x*4;
    int p  = p0 + wave;
    int n  = p / PX, px = p % PX;

    float xi[3], sz[3];
    #pragma unroll
    for (int t = 0; t < 3; t++){
        int c = lane + 64*t;
        float xr = 0.f, zr = 0.f;
        #pragma unroll
        for (int q = 0; q < CSPLIT; q++){
            const float* ap = acc + ((long)(q*NB + n)*PX + px)*CO;
            xr += ap[c]; zr += ap[CI + c];
        }
        xi[t] = siluf(xr*c1w[c*4 + 3] + c1b[c]);
        sz[t] = siluf(zr);
    }

    float dbc[NDBC];
    #pragma unroll
    for (int j = 0; j < NDBC; j++){
        float s = 0.f;
        #pragma unroll
        for (int t = 0; t < 3; t++) s += xi[t]*xpw[j*CI + lane + 64*t];
        dbc[j] = s;
    }
    #pragma unroll
    for (int step = 1; step < 64; step <<= 1){
        #pragma unroll
        for (int j = 0; j < NDBC; j++) dbc[j] += __shfl_xor(dbc[j], step, 64);
    }
    float BC = 0.f;
    #pragma unroll
    for (int s = 0; s < 16; s++) BC += dbc[6+s]*dbc[22+s];

    #pragma unroll
    for (int t = 0; t < 3; t++){
        int c = lane + 64*t;
        float dl = dtb[c];
        #pragma unroll
        for (int r = 0; r < DTR; r++) dl += dbc[r]*dtw[c*DTR + r];
        dl = softplusf(dl);
        gl[wave][c] = xi[t]*(dl*BC + Dp[c])*sz[t];
    }
    __syncthreads();

    for (int idx = threadIdx.x; idx < 4*CM; idx += 256){
        int pl = idx / CM, m = idx % CM;
        int pp = p0 + pl;
        int nn = pp / PX, ppx = pp % PX;
        const float* g = gl[pl];
        float s0 = 0.f, s1 = 0.f, s2 = 0.f, s3 = 0.f;
        for (int c = 0; c < CI; c += 4){
            s0 += g[c+0]*wpT[(c+0)*CM + m];
            s1 += g[c+1]*wpT[(c+1)*CM + m];
            s2 += g[c+2]*wpT[(c+2)*CM + m];
            s3 += g[c+3]*wpT[(c+3)*CM + m];
        }
        float s = (s0+s1) + (s2+s3);
        s += xres[(long)nn*nStrR + (long)m*cStrR + ppx];
        dst[(nn*CM + m)*PX + ppx] = s;
    }
}

extern "C" void kernel_launch(void* const* d_in, const int* in_sizes, int n_in,
                              void* d_out, int out_size, void* d_ws, size_t ws_size,
                              hipStream_t stream) {
    const float* x_in = (const float*)d_in[0];   // (2,96,8,24,24)
    const float* ipw  = (const float*)d_in[1];   // (2,384,96,1,3,3)
    const float* c1w  = (const float*)d_in[2];   // (2,192,1,4,1,1)
    const float* c1b  = (const float*)d_in[3];   // (2,192)
    const float* xpw  = (const float*)d_in[4];   // (2,38,192)
    const float* dtw  = (const float*)d_in[5];   // (2,192,6)
    const float* dtb  = (const float*)d_in[6];   // (2,192)
    // d_in[7] = A_log: unused at depth 0 (multiplies h[-1]=0)
    const float* Dp   = (const float*)d_in[8];   // (2,192)
    const float* opw  = (const float*)d_in[9];   // (2,96,192)
    const float* nw   = (const float*)d_in[10];  // (2,1,96,1,1,1)

    float* ws  = (float*)d_ws;
    float* wQ  = ws;                         // 2*294912
    float* wR  = wQ  + 2*WQ_L;               // 2*36864
    float* wpT = wR  + 2*WR_L;               // 2*18432
    float* acc = wpT + 2*WP_L;               // 4*2*576*384 = 1769472
    float* x1  = acc + (long)CSPLIT*NB*PX*CO;// 110592

    prep_k<<<(NW_IN + 2*CI*CM + 255)/256, 256, 0, stream>>>(ipw, opw, wQ, wR, wpT);

    // ---- layer 0 (input: depth-0 slice of x, strides of (2,96,8,24,24))
    conv_k<<<dim3(NB*HP, 6, CSPLIT), 256, 0, stream>>>(
        x_in, 96L*8*PX, 8L*PX, nw, wQ, wR, acc);
    ssmproj_k<<<NB*PX/4, 256, 0, stream>>>(
        acc, c1w, c1b, xpw, dtw, dtb, Dp, wpT,
        x_in, 96L*8*PX, 8L*PX, x1);

    // ---- layer 1 (input x1 packed (2,96,24,24); writes final output)
    conv_k<<<dim3(NB*HP, 6, CSPLIT), 256, 0, stream>>>(
        x1, 96L*PX, (long)PX, nw + CM, wQ + WQ_L, wR + WR_L, acc);
    ssmproj_k<<<NB*PX/4, 256, 0, stream>>>(
        acc, c1w + CI*4, c1b + CI, xpw + NDBC*CI, dtw + CI*DTR, dtb + CI, Dp + CI, wpT + WP_L,
        x1, 96L*PX, (long)PX, (float*)d_out);
}